// Round 5
// baseline (218.418 us; speedup 1.0000x reference)
//
#include <hip/hip_runtime.h>

#define USE_MFMA 1

#define BB   8
#define CC   128
#define HH   64
#define WW   64
#define HWW  (HH * WW)      // 4096
#define OFFC 18
#define PP   128            // deform output channels
#define KK9  9

typedef __attribute__((ext_vector_type(8))) short bf16x8;
typedef __attribute__((ext_vector_type(4))) float f32x4;

// round-to-nearest-even fp32 -> bf16 bits
__device__ __forceinline__ unsigned bf16_rtne(float v) {
  unsigned u = __float_as_uint(v);
  return (u + 0x7fffu + ((u >> 16) & 1u)) >> 16;
}

#if USE_MFMA
// ---------------------------------------------------------------------------
// Kernel A: transpose x [B][C][H][W] -> xt [B][H][W][C] so bilinear gathers
// load channels as contiguous float4. Block = (b,h): 128c x 64w tile via LDS.
// ---------------------------------------------------------------------------
__global__ __launch_bounds__(256) void k_xt(
    const float* __restrict__ x, float* __restrict__ xt) {
  __shared__ float s[CC][WW + 1];   // +1 pad
  const int t = threadIdx.x;
  const int b = blockIdx.x >> 6;
  const int hh = blockIdx.x & 63;
  const float* xp = x + (size_t)b * CC * HWW + hh * WW;
  const int w = t & 63;
#pragma unroll
  for (int p = 0; p < 32; ++p) {
    int c = p * 4 + (t >> 6);
    s[c][w] = xp[(size_t)c * HWW + w];   // coalesced 64-float rows
  }
  __syncthreads();
  float* op = xt + ((size_t)(b * HH + hh) * WW) * CC;
#pragma unroll
  for (int p = 0; p < 8; ++p) {
    int flat = p * 256 + t;            // 2048 float4 stores
    int ww = flat >> 5, cg = flat & 31;
    float4 v = make_float4(s[cg * 4][ww], s[cg * 4 + 1][ww],
                           s[cg * 4 + 2][ww], s[cg * 4 + 3][ww]);
    *(float4*)&op[ww * CC + cg * 4] = v;  // coalesced
  }
}

// ---------------------------------------------------------------------------
// Kernel B: pre-pack deform weight into per-lane A-fragments (hi/lo split).
// K = tap*128 + c (tap-major). A-frag (16x16x32): lane l holds
// A[o = l&15][k = (l>>4)*8 + j]. Out: [kstep 36][otile 8][lane 64][8].
// ---------------------------------------------------------------------------
__global__ __launch_bounds__(256) void k_wt2(
    const float* __restrict__ dfw,   // [P][C][3][3]
    short* __restrict__ whi, short* __restrict__ wlo) {
  int tid = blockIdx.x * 256 + threadIdx.x;  // 36*8*64 = 18432
  if (tid >= 36 * 8 * 64) return;
  int l  = tid & 63;
  int ot = (tid >> 6) & 7;
  int s  = tid >> 9;                 // kstep 0..35
  int o  = ot * 16 + (l & 15);
  bf16x8 hv, lv;
#pragma unroll
  for (int j = 0; j < 8; ++j) {
    int K   = s * 32 + (l >> 4) * 8 + j;
    int tap = K >> 7;
    int c   = K & 127;
    float v = dfw[((size_t)o * CC + c) * KK9 + tap];
    unsigned hb = bf16_rtne(v);
    float lo = v - __uint_as_float(hb << 16);
    hv[j] = (short)hb;
    lv[j] = (short)bf16_rtne(lo);
  }
  *(bf16x8*)&whi[(size_t)tid * 8] = hv;
  *(bf16x8*)&wlo[(size_t)tid * 8] = lv;
}

// ---------------------------------------------------------------------------
// Kernel C: fully fused dwconv+BN+ReLU + offset 1x1 + deformable conv.
// Block = (b,row): out tile 128o x 64w, 4 waves, 56.8 KB LDS (2 blocks/CU).
// Phase -1: stage dw weights / folded BN / offset weights (LDS).
// Phase 0 : h for this row inline (3x3 dw + scale/shift + relu) feeding the
//           1x1 offset conv, 4-way c-split partials.
// Phase 1 : reduce partials -> bilinear corner tables (validity folded into
//           weights, clamped indices pre-multiplied by C for NHWC).
// Main    : per tap: NHWC float4 gathers -> bf16 hi/lo -> swizzled LDS ->
//           4 MFMA K-steps (3-term bf16 split, fp32 accum). No cross-tap
//           register pipeline: latency hiding comes from 2 blocks/CU.
// ---------------------------------------------------------------------------
__global__ __launch_bounds__(256) void k_deform_mfma(
    const float* __restrict__ x,     // [B][C][H][W]  (for dwconv)
    const float* __restrict__ xt,    // [B][H][W][C]  (for gathers)
    const float* __restrict__ dww,   // [C][1][3][3]
    const float* __restrict__ dwb,
    const float* __restrict__ gamma,
    const float* __restrict__ beta,
    const float* __restrict__ mean,
    const float* __restrict__ var,
    const float* __restrict__ ow,    // [18][128]
    const short* __restrict__ whi,   // packed A hi
    const short* __restrict__ wlo,   // packed A lo
    float* __restrict__ out) {       // [B][P][H][W]
  __shared__ union {
    struct { float part[4][OFFC][WW]; float ow[OFFC * CC]; } pre;  // 27648 B
    struct { short hi[8192]; short lo[8192]; } S;                  // 32768 B
  } sm;
  __shared__ int4   s_bidx[576];
  __shared__ float4 s_bwt[576];
  __shared__ float  s_dwwf[CC * KK9];
  __shared__ float  s_scale[CC];
  __shared__ float  s_shift[CC];

  const int t = threadIdx.x;
  const int b = blockIdx.x >> 6;
  const int row = blockIdx.x & 63;

  // ---- phase -1: stage small weights ----
  for (int i = t; i < CC * KK9; i += 256) s_dwwf[i] = dww[i];
  for (int i = t; i < OFFC * CC; i += 256) sm.pre.ow[i] = ow[i];
  if (t < CC) {
    float sc = gamma[t] * rsqrtf(var[t] + 1e-5f);
    s_scale[t] = sc;
    s_shift[t] = (dwb[t] - mean[t]) * sc + beta[t];
  }
  __syncthreads();

  // ---- phase 0: h (inline dwconv+bn+relu) -> offset 1x1 partials ----
  {
    const int w = t & 63, cg = t >> 6;   // cg wave-uniform
    const float* xb = x + (size_t)b * CC * HWW;
    float accO[OFFC];
#pragma unroll
    for (int o = 0; o < OFFC; ++o) accO[o] = 0.0f;
    for (int cc = 0; cc < 32; ++cc) {
      int c = cg * 32 + cc;
      const float* xc = xb + (size_t)c * HWW;
      float conv = 0.0f;
#pragma unroll
      for (int ky = 0; ky < 3; ++ky) {
        int y = row - 1 + ky;
        if (y < 0 || y >= HH) continue;       // block-uniform branch
        const float* xr = xc + y * WW;
#pragma unroll
        for (int kx = 0; kx < 3; ++kx) {
          int ww2 = w - 1 + kx;
          float xv = (ww2 >= 0 && ww2 < WW) ? xr[ww2 & 63] : 0.0f;
          conv = fmaf(xv, s_dwwf[c * KK9 + ky * 3 + kx], conv);
        }
      }
      float hv = fmaxf(fmaf(conv, s_scale[c], s_shift[c]), 0.0f);
#pragma unroll
      for (int o = 0; o < OFFC; ++o)
        accO[o] = fmaf(hv, sm.pre.ow[o * CC + c], accO[o]);
    }
#pragma unroll
    for (int o = 0; o < OFFC; ++o) sm.pre.part[cg][o][w] = accO[o];
  }
  __syncthreads();

  // ---- phase 1: reduce partials, build bilinear tables (NHWC indices) ----
  for (int i = t; i < 576; i += 256) {
    int k = i >> 6, w = i & 63;
    float dy = sm.pre.part[0][2 * k][w] + sm.pre.part[1][2 * k][w] +
               sm.pre.part[2][2 * k][w] + sm.pre.part[3][2 * k][w];
    float dx = sm.pre.part[0][2 * k + 1][w] + sm.pre.part[1][2 * k + 1][w] +
               sm.pre.part[2][2 * k + 1][w] + sm.pre.part[3][2 * k + 1][w];
    int ky = k / 3;
    int kx = k - ky * 3;
    float py = (float)(row - 1 + ky) + dy;
    float px = (float)(w - 1 + kx) + dx;
    float y0f = floorf(py), x0f = floorf(px);
    float wy = py - y0f, wx = px - x0f;
    int y0 = (int)y0f, x0 = (int)x0f;
    int y1 = y0 + 1, x1 = x0 + 1;
    float vy0 = (y0 >= 0 && y0 < HH) ? 1.0f : 0.0f;
    float vy1 = (y1 >= 0 && y1 < HH) ? 1.0f : 0.0f;
    float vx0 = (x0 >= 0 && x0 < WW) ? 1.0f : 0.0f;
    float vx1 = (x1 >= 0 && x1 < WW) ? 1.0f : 0.0f;
    int y0c = min(max(y0, 0), HH - 1), y1c = min(max(y1, 0), HH - 1);
    int x0c = min(max(x0, 0), WW - 1), x1c = min(max(x1, 0), WW - 1);
    s_bidx[i] = make_int4((y0c * WW + x0c) * CC, (y0c * WW + x1c) * CC,
                          (y1c * WW + x0c) * CC, (y1c * WW + x1c) * CC);
    float omy = 1.0f - wy, omx = 1.0f - wx;
    s_bwt[i] = make_float4(omy * omx * vy0 * vx0, omy * wx * vy0 * vx1,
                           wy * omx * vy1 * vx0, wy * wx * vy1 * vx1);
  }
  __syncthreads();  // part/ow reads done before S overwrites union

  // ---- main loop ----
  const int lane = t & 63;
  const int wid  = t >> 6;
  const int sw   = t & 63;           // sampling w column
  const float* xtb = xt + (size_t)b * HWW * CC;

  f32x4 acc[2][4];
#pragma unroll
  for (int oi = 0; oi < 2; ++oi)
#pragma unroll
    for (int wt = 0; wt < 4; ++wt) acc[oi][wt] = (f32x4)0.0f;

  for (int tap = 0; tap < KK9; ++tap) {
    __syncthreads();   // prior MFMA reads of S done (first iter: phase-1 done)

    // ---- sample this tap straight into LDS (w fixed per thread, 32 ch) ----
    {
      int4   ii = s_bidx[tap * 64 + sw];
      float4 bw = s_bwt[tap * 64 + sw];
      const float* p00 = xtb + ii.x;
      const float* p01 = xtb + ii.y;
      const float* p10 = xtb + ii.z;
      const float* p11 = xtb + ii.w;
      const int c0 = wid * 32;
#pragma unroll
      for (int n = 0; n < 4; ++n) {
        int ch = c0 + n * 8;
        float4 a0 = *(const float4*)(p00 + ch), a1 = *(const float4*)(p00 + ch + 4);
        float4 b0 = *(const float4*)(p01 + ch), b1 = *(const float4*)(p01 + ch + 4);
        float4 g0 = *(const float4*)(p10 + ch), g1 = *(const float4*)(p10 + ch + 4);
        float4 d0 = *(const float4*)(p11 + ch), d1 = *(const float4*)(p11 + ch + 4);
        bf16x8 hv, lv;
#pragma unroll
        for (int j = 0; j < 4; ++j) {
          float v = bw.x * a0[j] + bw.y * b0[j] + bw.z * g0[j] + bw.w * d0[j];
          unsigned hb = bf16_rtne(v);
          float lo = v - __uint_as_float(hb << 16);
          hv[j] = (short)hb;
          lv[j] = (short)bf16_rtne(lo);
        }
#pragma unroll
        for (int j = 0; j < 4; ++j) {
          float v = bw.x * a1[j] + bw.y * b1[j] + bw.z * g1[j] + bw.w * d1[j];
          unsigned hb = bf16_rtne(v);
          float lo = v - __uint_as_float(hb << 16);
          hv[4 + j] = (short)hb;
          lv[4 + j] = (short)bf16_rtne(lo);
        }
        int cb = wid * 4 + n;
        int idx = sw * 128 + ((cb ^ (sw & 7)) << 3);  // swizzled granule
        *(bf16x8*)&sm.S.hi[idx] = hv;
        *(bf16x8*)&sm.S.lo[idx] = lv;
      }
    }
    __syncthreads();   // S ready

    // ---- 4 MFMA K-steps over this tap's 128 channels, 3-term split ----
#pragma unroll
    for (int cstep = 0; cstep < 4; ++cstep) {
      int s = tap * 4 + cstep;
      bf16x8 ah[2], al[2];
#pragma unroll
      for (int oi = 0; oi < 2; ++oi) {
        size_t off = ((size_t)(s * 8 + (wid * 2 + oi)) * 64 + lane) * 8;
        ah[oi] = *(const bf16x8*)&whi[off];
        al[oi] = *(const bf16x8*)&wlo[off];
      }
      bf16x8 bh[4], bl[4];
#pragma unroll
      for (int wt = 0; wt < 4; ++wt) {
        int rw = wt * 16 + (lane & 15);
        int cbr = cstep * 4 + (lane >> 4);
        int idx = rw * 128 + ((cbr ^ (rw & 7)) << 3);
        bh[wt] = *(const bf16x8*)&sm.S.hi[idx];
        bl[wt] = *(const bf16x8*)&sm.S.lo[idx];
      }
#pragma unroll
      for (int oi = 0; oi < 2; ++oi)
#pragma unroll
        for (int wt = 0; wt < 4; ++wt) {
          acc[oi][wt] = __builtin_amdgcn_mfma_f32_16x16x32_bf16(
              ah[oi], bh[wt], acc[oi][wt], 0, 0, 0);
          acc[oi][wt] = __builtin_amdgcn_mfma_f32_16x16x32_bf16(
              ah[oi], bl[wt], acc[oi][wt], 0, 0, 0);
          acc[oi][wt] = __builtin_amdgcn_mfma_f32_16x16x32_bf16(
              al[oi], bh[wt], acc[oi][wt], 0, 0, 0);
        }
    }
  }

  // ---- epilogue: C/D layout col=lane&15, row=(lane>>4)*4+reg (m89) ----
#pragma unroll
  for (int oi = 0; oi < 2; ++oi) {
    int o = (wid * 2 + oi) * 16 + (lane >> 4) * 4;
#pragma unroll
    for (int wt = 0; wt < 4; ++wt) {
      int wcol = wt * 16 + (lane & 15);
      float* op = out + (((size_t)b * PP + o) * HH + row) * WW + wcol;
#pragma unroll
      for (int r = 0; r < 4; ++r) op[(size_t)r * HWW] = acc[oi][wt][r];
    }
  }
}
#else
// ---------------------------------------------------------------------------
// fp32 fallback path (kept for bisection)
// ---------------------------------------------------------------------------
__global__ __launch_bounds__(256) void k_dw_bn_relu(
    const float* __restrict__ x, const float* __restrict__ dww,
    const float* __restrict__ dwb, const float* __restrict__ gamma,
    const float* __restrict__ beta, const float* __restrict__ mean,
    const float* __restrict__ var, float* __restrict__ hout) {
  int idx = blockIdx.x * 256 + threadIdx.x;
  if (idx >= BB * CC * HWW) return;
  int w = idx & (WW - 1);
  int h = (idx >> 6) & (HH - 1);
  int c = (idx >> 12) & (CC - 1);
  const float* xp = x + (size_t)(idx >> 12) * HWW;
  const float* wp = dww + c * 9;
  float acc = 0.0f;
#pragma unroll
  for (int ky = 0; ky < 3; ++ky) {
    int yy = h + ky - 1;
    if (yy < 0 || yy >= HH) continue;
#pragma unroll
    for (int kx = 0; kx < 3; ++kx) {
      int xx = w + kx - 1;
      if (xx < 0 || xx >= WW) continue;
      acc = fmaf(xp[yy * WW + xx], wp[ky * 3 + kx], acc);
    }
  }
  acc += dwb[c];
  float inv = rsqrtf(var[c] + 1e-5f);
  float v = (acc - mean[c]) * (gamma[c] * inv) + beta[c];
  hout[idx] = fmaxf(v, 0.0f);
}

__global__ __launch_bounds__(256) void k_wt(
    const float* __restrict__ dw, float* __restrict__ dwt) {
  int idx = blockIdx.x * 256 + threadIdx.x;
  if (idx >= PP * CC * KK9) return;
  int k = idx % KK9;
  int c = (idx / KK9) % CC;
  int o = idx / (KK9 * CC);
  dwt[(size_t)c * (KK9 * PP) + k * PP + o] = dw[idx];
}

__global__ __launch_bounds__(256) void k_deform_fp32(
    const float* __restrict__ x, const float* __restrict__ h,
    const float* __restrict__ ow, const float* __restrict__ dwt,
    float* __restrict__ out) {
  __shared__ float  s_part[4][OFFC][WW];
  __shared__ int4   s_bidx[576];
  __shared__ float4 s_bwt[576];
  __shared__ float  s_S[2][576];
  __shared__ float  s_W[2][KK9 * PP];
  const int t = threadIdx.x;
  const int b = blockIdx.x >> 6;
  const int row = blockIdx.x & 63;
  {
    const int w = t & 63, cg = t >> 6;
    const float* hp = h + ((size_t)b * CC + cg * 32) * HWW + row * WW + w;
    const float* owp = ow + cg * 32;
    float acc[OFFC];
#pragma unroll
    for (int o = 0; o < OFFC; ++o) acc[o] = 0.0f;
    for (int c = 0; c < 32; ++c) {
      float hv = hp[(size_t)c * HWW];
#pragma unroll
      for (int o = 0; o < OFFC; ++o) acc[o] = fmaf(hv, owp[o * CC + c], acc[o]);
    }
#pragma unroll
    for (int o = 0; o < OFFC; ++o) s_part[cg][o][w] = acc[o];
  }
  __syncthreads();
  for (int i = t; i < 576; i += 256) {
    int k = i >> 6, w = i & 63;
    float dy = s_part[0][2 * k][w] + s_part[1][2 * k][w] +
               s_part[2][2 * k][w] + s_part[3][2 * k][w];
    float dx = s_part[0][2 * k + 1][w] + s_part[1][2 * k + 1][w] +
               s_part[2][2 * k + 1][w] + s_part[3][2 * k + 1][w];
    int ky = k / 3, kx = k - ky * 3;
    float py = (float)(row - 1 + ky) + dy;
    float px = (float)(w - 1 + kx) + dx;
    float y0f = floorf(py), x0f = floorf(px);
    float wy = py - y0f, wx = px - x0f;
    int y0 = (int)y0f, x0 = (int)x0f, y1 = y0 + 1, x1 = x0 + 1;
    float vy0 = (y0 >= 0 && y0 < HH) ? 1.0f : 0.0f;
    float vy1 = (y1 >= 0 && y1 < HH) ? 1.0f : 0.0f;
    float vx0 = (x0 >= 0 && x0 < WW) ? 1.0f : 0.0f;
    float vx1 = (x1 >= 0 && x1 < WW) ? 1.0f : 0.0f;
    int y0c = min(max(y0, 0), HH - 1), y1c = min(max(y1, 0), HH - 1);
    int x0c = min(max(x0, 0), WW - 1), x1c = min(max(x1, 0), WW - 1);
    s_bidx[i] = make_int4(y0c * WW + x0c, y0c * WW + x1c,
                          y1c * WW + x0c, y1c * WW + x1c);
    float omy = 1.0f - wy, omx = 1.0f - wx;
    s_bwt[i] = make_float4(omy * omx * vy0 * vx0, omy * wx * vy0 * vx1,
                           wy * omx * vy1 * vx0, wy * wx * vy1 * vx1);
  }
  __syncthreads();
  const int og = t >> 3, hg = t & 7;
  float acc[4][8];
#pragma unroll
  for (int oi = 0; oi < 4; ++oi)
#pragma unroll
    for (int j = 0; j < 8; ++j) acc[oi][j] = 0.0f;
  const float* xb = x + (size_t)b * CC * HWW;
  auto stage = [&](int c) {
    int buf = c & 1;
    const float4* wp4 = (const float4*)(dwt + (size_t)c * (KK9 * PP));
    float4* sW4 = (float4*)s_W[buf];
    sW4[t] = wp4[t];
    if (t < 32) sW4[256 + t] = wp4[256 + t];
    const float* xp = xb + (size_t)c * HWW;
    for (int i = t; i < 576; i += 256) {
      int4 ii = s_bidx[i];
      float4 bw = s_bwt[i];
      s_S[buf][i] = bw.x * xp[ii.x] + bw.y * xp[ii.y] +
                    bw.z * xp[ii.z] + bw.w * xp[ii.w];
    }
  };
  stage(0);
  for (int c = 0; c < CC; ++c) {
    __syncthreads();
    if (c + 1 < CC) stage(c + 1);
    const int buf = c & 1;
    const float* Wb = s_W[buf];
    const float* Sb = s_S[buf];
#pragma unroll
    for (int k = 0; k < KK9; ++k) {
      float4 wv = *(const float4*)&Wb[k * PP + og * 4];
      float4 s0 = *(const float4*)&Sb[k * 64 + hg * 8];
      float4 s1 = *(const float4*)&Sb[k * 64 + hg * 8 + 4];
      float wvs[4] = {wv.x, wv.y, wv.z, wv.w};
#pragma unroll
      for (int oi = 0; oi < 4; ++oi) {
        float wv1 = wvs[oi];
        acc[oi][0] = fmaf(wv1, s0.x, acc[oi][0]);
        acc[oi][1] = fmaf(wv1, s0.y, acc[oi][1]);
        acc[oi][2] = fmaf(wv1, s0.z, acc[oi][2]);
        acc[oi][3] = fmaf(wv1, s0.w, acc[oi][3]);
        acc[oi][4] = fmaf(wv1, s1.x, acc[oi][4]);
        acc[oi][5] = fmaf(wv1, s1.y, acc[oi][5]);
        acc[oi][6] = fmaf(wv1, s1.z, acc[oi][6]);
        acc[oi][7] = fmaf(wv1, s1.w, acc[oi][7]);
      }
    }
  }
#pragma unroll
  for (int oi = 0; oi < 4; ++oi) {
    float* op = out + ((size_t)(b * PP + og * 4 + oi) * HH + row) * WW + hg * 8;
    *(float4*)op = make_float4(acc[oi][0], acc[oi][1], acc[oi][2], acc[oi][3]);
    *((float4*)op + 1) = make_float4(acc[oi][4], acc[oi][5], acc[oi][6], acc[oi][7]);
  }
}
#endif

// ---------------------------------------------------------------------------
extern "C" void kernel_launch(void* const* d_in, const int* in_sizes, int n_in,
                              void* d_out, int out_size, void* d_ws, size_t ws_size,
                              hipStream_t stream) {
  const float* x     = (const float*)d_in[0];
  const float* dww   = (const float*)d_in[1];
  const float* dwb   = (const float*)d_in[2];
  const float* gamma = (const float*)d_in[3];
  const float* beta  = (const float*)d_in[4];
  const float* mean  = (const float*)d_in[5];
  const float* var   = (const float*)d_in[6];
  const float* offw  = (const float*)d_in[7];  // [18][128][1][1]
  const float* dfw   = (const float*)d_in[8];  // [128][128][3][3]
  float* out = (float*)d_out;

#if USE_MFMA
  // ws layout (floats): xt[4194304] | whi | wlo (147456 shorts each)
  float* xt_ws = (float*)d_ws;
  short* whi = (short*)(xt_ws + (size_t)BB * CC * HWW);
  short* wlo = whi + 36 * 8 * 64 * 8;
  k_xt<<<BB * HH, 256, 0, stream>>>(x, xt_ws);
  k_wt2<<<72, 256, 0, stream>>>(dfw, whi, wlo);
  k_deform_mfma<<<BB * HH, 256, 0, stream>>>(
      x, xt_ws, dww, dwb, gamma, beta, mean, var, offw, whi, wlo, out);
#else
  float* h_ws   = (float*)d_ws;
  float* dwt_ws = h_ws + (size_t)BB * CC * HWW;
  k_dw_bn_relu<<<(BB * CC * HWW) / 256, 256, 0, stream>>>(
      x, dww, dwb, gamma, beta, mean, var, h_ws);
  k_wt<<<(PP * CC * KK9 + 255) / 256, 256, 0, stream>>>(dfw, dwt_ws);
  k_deform_fp32<<<BB * HH, 256, 0, stream>>>(x, h_ws, offw, dwt_ws, out);
#endif
}

// Round 8
// 204.604 us; speedup vs baseline: 1.0675x; 1.0675x over previous
//
#include <hip/hip_runtime.h>

#define BB   8
#define CC   128
#define HH   64
#define WW   64
#define HWW  (HH * WW)      // 4096
#define OFFC 18
#define PP   128            // deform output channels
#define KK9  9

typedef __attribute__((ext_vector_type(8))) short bf16x8;
typedef __attribute__((ext_vector_type(4))) float f32x4;

// round-to-nearest-even fp32 -> bf16 bits
__device__ __forceinline__ unsigned bf16_rtne(float v) {
  unsigned u = __float_as_uint(v);
  return (u + 0x7fffu + ((u >> 16) & 1u)) >> 16;
}

// ---------------------------------------------------------------------------
// Kernel A (fused prep):
//  blocks 0..511   : transpose x [B][C][H][W] -> xt [B][H][W][C], XCD-aware
//                    (b = bid&7 so xt[b] is produced on the XCD that will
//                    consume it in k_deform_mfma).
//  blocks 512..583 : pack deform weight into per-lane MFMA A-fragments,
//                    hi/lo bf16 split. K = tap*128 + c (tap-major).
//                    A-frag (16x16x32): lane l holds A[o=l&15][k=(l>>4)*8+j].
//                    Out: [kstep 36][otile 8][lane 64][8].
// ---------------------------------------------------------------------------
__global__ __launch_bounds__(256) void k_prep(
    const float* __restrict__ x, float* __restrict__ xt,
    const float* __restrict__ dfw,   // [P][C][3][3]
    short* __restrict__ whi, short* __restrict__ wlo) {
  const int t = threadIdx.x;
  if (blockIdx.x < 512) {
    __shared__ float s[CC][WW + 1];   // +1 pad
    const int b  = blockIdx.x & 7;    // XCD-local batch
    const int hh = blockIdx.x >> 3;
    const float* xp = x + (size_t)b * CC * HWW + hh * WW;
    const int w = t & 63;
#pragma unroll
    for (int p = 0; p < 32; ++p) {
      int c = p * 4 + (t >> 6);
      s[c][w] = xp[(size_t)c * HWW + w];   // coalesced 64-float rows
    }
    __syncthreads();
    float* op = xt + ((size_t)(b * HH + hh) * WW) * CC;
#pragma unroll
    for (int p = 0; p < 8; ++p) {
      int flat = p * 256 + t;            // 2048 float4 stores
      int ww = flat >> 5, cg = flat & 31;
      float4 v = make_float4(s[cg * 4][ww], s[cg * 4 + 1][ww],
                             s[cg * 4 + 2][ww], s[cg * 4 + 3][ww]);
      *(float4*)&op[ww * CC + cg * 4] = v;  // coalesced
    }
  } else {
    int tid = (blockIdx.x - 512) * 256 + t;  // 36*8*64 = 18432
    if (tid >= 36 * 8 * 64) return;
    int l  = tid & 63;
    int ot = (tid >> 6) & 7;
    int s  = tid >> 9;                 // kstep 0..35
    int o  = ot * 16 + (l & 15);
    bf16x8 hv, lv;
#pragma unroll
    for (int j = 0; j < 8; ++j) {
      int K   = s * 32 + (l >> 4) * 8 + j;
      int tap = K >> 7;
      int c   = K & 127;
      float v = dfw[((size_t)o * CC + c) * KK9 + tap];
      unsigned hb = bf16_rtne(v);
      float lo = v - __uint_as_float(hb << 16);
      hv[j] = (short)hb;
      lv[j] = (short)bf16_rtne(lo);
    }
    *(bf16x8*)&whi[(size_t)tid * 8] = hv;
    *(bf16x8*)&wlo[(size_t)tid * 8] = lv;
  }
}

// ---------------------------------------------------------------------------
// Kernel C: fully fused dwconv+BN+ReLU + offset 1x1 + deformable conv.
// XCD-aware decomposition: b = blockIdx&7, row = blockIdx>>3 — all 64 blocks
// of one batch run on one XCD, whose 4 MB L2 then holds x[b]+xt[b] (4 MB).
// LDS = 50.5 KB. Occupancy is grid-capped at 2 blocks/CU (512 blocks).
// Phase 0 : h for this row inline (3x3 dw + scale/shift + relu) feeding the
//           1x1 offset conv, 4-way c-split partials.
// Phase 1 : reduce partials -> bilinear corner tables (validity folded into
//           weights, clamped indices pre-multiplied by C for NHWC).
// Main    : per tap: NHWC float4 gathers (L2-hot) -> bf16 hi/lo -> swizzled
//           LDS -> 4 MFMA K-steps (3-term bf16 split, fp32 accum).
// ---------------------------------------------------------------------------
__global__ __launch_bounds__(256) void k_deform_mfma(
    const float* __restrict__ x,     // [B][C][H][W]  (for dwconv)
    const float* __restrict__ xt,    // [B][H][W][C]  (for gathers)
    const float* __restrict__ dww,   // [C][1][3][3]
    const float* __restrict__ dwb,
    const float* __restrict__ gamma,
    const float* __restrict__ beta,
    const float* __restrict__ mean,
    const float* __restrict__ var,
    const float* __restrict__ ow,    // [18][128]
    const short* __restrict__ whi,   // packed A hi
    const short* __restrict__ wlo,   // packed A lo
    float* __restrict__ out) {       // [B][P][H][W]
  __shared__ union {
    struct {
      float part[4][OFFC][WW];   // 18432 B
      float ow[OFFC * CC];       //  9216 B
      float dww[CC * KK9];       //  4608 B
      float scale[CC];           //   512 B
      float shift[CC];           //   512 B
    } pre;                                        // 33280 B
    struct { short hi[8192]; short lo[8192]; } S; // 32768 B
  } sm;
  __shared__ int4   s_bidx[576];   // 9216 B
  __shared__ float4 s_bwt[576];    // 9216 B
  // total LDS: 51712 B

  const int t = threadIdx.x;
  const int b   = blockIdx.x & 7;   // XCD-local batch
  const int row = blockIdx.x >> 3;

  // ---- phase -1: stage small weights ----
  for (int i = t; i < CC * KK9; i += 256) sm.pre.dww[i] = dww[i];
  for (int i = t; i < OFFC * CC; i += 256) sm.pre.ow[i] = ow[i];
  if (t < CC) {
    float sc = gamma[t] * rsqrtf(var[t] + 1e-5f);
    sm.pre.scale[t] = sc;
    sm.pre.shift[t] = (dwb[t] - mean[t]) * sc + beta[t];
  }
  __syncthreads();

  // ---- phase 0: h (inline dwconv+bn+relu) -> offset 1x1 partials ----
  {
    const int w = t & 63, cg = t >> 6;   // cg wave-uniform
    const float* xb = x + (size_t)b * CC * HWW;
    float accO[OFFC];
#pragma unroll
    for (int o = 0; o < OFFC; ++o) accO[o] = 0.0f;
    for (int cc = 0; cc < 32; ++cc) {
      int c = cg * 32 + cc;
      const float* xc = xb + (size_t)c * HWW;
      float conv = 0.0f;
#pragma unroll
      for (int ky = 0; ky < 3; ++ky) {
        int y = row - 1 + ky;
        if (y < 0 || y >= HH) continue;       // block-uniform branch
        const float* xr = xc + y * WW;
#pragma unroll
        for (int kx = 0; kx < 3; ++kx) {
          int ww2 = w - 1 + kx;
          float xv = (ww2 >= 0 && ww2 < WW) ? xr[ww2 & 63] : 0.0f;
          conv = fmaf(xv, sm.pre.dww[c * KK9 + ky * 3 + kx], conv);
        }
      }
      float hv = fmaxf(fmaf(conv, sm.pre.scale[c], sm.pre.shift[c]), 0.0f);
#pragma unroll
      for (int o = 0; o < OFFC; ++o)
        accO[o] = fmaf(hv, sm.pre.ow[o * CC + c], accO[o]);
    }
#pragma unroll
    for (int o = 0; o < OFFC; ++o) sm.pre.part[cg][o][w] = accO[o];
  }
  __syncthreads();

  // ---- phase 1: reduce partials, build bilinear tables (NHWC indices) ----
  for (int i = t; i < 576; i += 256) {
    int k = i >> 6, w = i & 63;
    float dy = sm.pre.part[0][2 * k][w] + sm.pre.part[1][2 * k][w] +
               sm.pre.part[2][2 * k][w] + sm.pre.part[3][2 * k][w];
    float dx = sm.pre.part[0][2 * k + 1][w] + sm.pre.part[1][2 * k + 1][w] +
               sm.pre.part[2][2 * k + 1][w] + sm.pre.part[3][2 * k + 1][w];
    int ky = k / 3;
    int kx = k - ky * 3;
    float py = (float)(row - 1 + ky) + dy;
    float px = (float)(w - 1 + kx) + dx;
    float y0f = floorf(py), x0f = floorf(px);
    float wy = py - y0f, wx = px - x0f;
    int y0 = (int)y0f, x0 = (int)x0f;
    int y1 = y0 + 1, x1 = x0 + 1;
    float vy0 = (y0 >= 0 && y0 < HH) ? 1.0f : 0.0f;
    float vy1 = (y1 >= 0 && y1 < HH) ? 1.0f : 0.0f;
    float vx0 = (x0 >= 0 && x0 < WW) ? 1.0f : 0.0f;
    float vx1 = (x1 >= 0 && x1 < WW) ? 1.0f : 0.0f;
    int y0c = min(max(y0, 0), HH - 1), y1c = min(max(y1, 0), HH - 1);
    int x0c = min(max(x0, 0), WW - 1), x1c = min(max(x1, 0), WW - 1);
    s_bidx[i] = make_int4((y0c * WW + x0c) * CC, (y0c * WW + x1c) * CC,
                          (y1c * WW + x0c) * CC, (y1c * WW + x1c) * CC);
    float omy = 1.0f - wy, omx = 1.0f - wx;
    s_bwt[i] = make_float4(omy * omx * vy0 * vx0, omy * wx * vy0 * vx1,
                           wy * omx * vy1 * vx0, wy * wx * vy1 * vx1);
  }
  __syncthreads();  // pre reads done before S overwrites union

  // ---- main loop ----
  const int lane = t & 63;
  const int wid  = t >> 6;
  const int sw   = t & 63;           // sampling w column
  const float* xtb = xt + (size_t)b * HWW * CC;

  f32x4 acc[2][4];
#pragma unroll
  for (int oi = 0; oi < 2; ++oi)
#pragma unroll
    for (int wt = 0; wt < 4; ++wt) acc[oi][wt] = (f32x4)0.0f;

  for (int tap = 0; tap < KK9; ++tap) {
    __syncthreads();   // prior MFMA reads of S done (first iter: phase-1 done)

    // ---- sample this tap straight into LDS (w fixed per thread, 32 ch) ----
    {
      int4   ii = s_bidx[tap * 64 + sw];
      float4 bw = s_bwt[tap * 64 + sw];
      const float* p00 = xtb + ii.x;
      const float* p01 = xtb + ii.y;
      const float* p10 = xtb + ii.z;
      const float* p11 = xtb + ii.w;
      const int c0 = wid * 32;
#pragma unroll
      for (int n = 0; n < 4; ++n) {
        int ch = c0 + n * 8;
        float4 a0 = *(const float4*)(p00 + ch), a1 = *(const float4*)(p00 + ch + 4);
        float4 b0 = *(const float4*)(p01 + ch), b1 = *(const float4*)(p01 + ch + 4);
        float4 g0 = *(const float4*)(p10 + ch), g1 = *(const float4*)(p10 + ch + 4);
        float4 d0 = *(const float4*)(p11 + ch), d1 = *(const float4*)(p11 + ch + 4);
        bf16x8 hv, lv;
#pragma unroll
        for (int j = 0; j < 4; ++j) {
          float v = bw.x * a0[j] + bw.y * b0[j] + bw.z * g0[j] + bw.w * d0[j];
          unsigned hb = bf16_rtne(v);
          float lo = v - __uint_as_float(hb << 16);
          hv[j] = (short)hb;
          lv[j] = (short)bf16_rtne(lo);
        }
#pragma unroll
        for (int j = 0; j < 4; ++j) {
          float v = bw.x * a1[j] + bw.y * b1[j] + bw.z * g1[j] + bw.w * d1[j];
          unsigned hb = bf16_rtne(v);
          float lo = v - __uint_as_float(hb << 16);
          hv[4 + j] = (short)hb;
          lv[4 + j] = (short)bf16_rtne(lo);
        }
        int cb = wid * 4 + n;
        int idx = sw * 128 + ((cb ^ (sw & 7)) << 3);  // swizzled granule
        *(bf16x8*)&sm.S.hi[idx] = hv;
        *(bf16x8*)&sm.S.lo[idx] = lv;
      }
    }
    __syncthreads();   // S ready

    // ---- 4 MFMA K-steps over this tap's 128 channels, 3-term split ----
#pragma unroll
    for (int cstep = 0; cstep < 4; ++cstep) {
      int s = tap * 4 + cstep;
      bf16x8 ah[2], al[2];
#pragma unroll
      for (int oi = 0; oi < 2; ++oi) {
        size_t off = ((size_t)(s * 8 + (wid * 2 + oi)) * 64 + lane) * 8;
        ah[oi] = *(const bf16x8*)&whi[off];
        al[oi] = *(const bf16x8*)&wlo[off];
      }
      bf16x8 bh[4], bl[4];
#pragma unroll
      for (int wt = 0; wt < 4; ++wt) {
        int rw = wt * 16 + (lane & 15);
        int cbr = cstep * 4 + (lane >> 4);
        int idx = rw * 128 + ((cbr ^ (rw & 7)) << 3);
        bh[wt] = *(const bf16x8*)&sm.S.hi[idx];
        bl[wt] = *(const bf16x8*)&sm.S.lo[idx];
      }
#pragma unroll
      for (int oi = 0; oi < 2; ++oi)
#pragma unroll
        for (int wt = 0; wt < 4; ++wt) {
          acc[oi][wt] = __builtin_amdgcn_mfma_f32_16x16x32_bf16(
              ah[oi], bh[wt], acc[oi][wt], 0, 0, 0);
          acc[oi][wt] = __builtin_amdgcn_mfma_f32_16x16x32_bf16(
              ah[oi], bl[wt], acc[oi][wt], 0, 0, 0);
          acc[oi][wt] = __builtin_amdgcn_mfma_f32_16x16x32_bf16(
              al[oi], bh[wt], acc[oi][wt], 0, 0, 0);
        }
    }
  }

  // ---- epilogue: C/D layout col=lane&15, row=(lane>>4)*4+reg (m89) ----
#pragma unroll
  for (int oi = 0; oi < 2; ++oi) {
    int o = (wid * 2 + oi) * 16 + (lane >> 4) * 4;
#pragma unroll
    for (int wt = 0; wt < 4; ++wt) {
      int wcol = wt * 16 + (lane & 15);
      float* op = out + (((size_t)b * PP + o) * HH + row) * WW + wcol;
#pragma unroll
      for (int r = 0; r < 4; ++r) op[(size_t)r * HWW] = acc[oi][wt][r];
    }
  }
}

// ---------------------------------------------------------------------------
extern "C" void kernel_launch(void* const* d_in, const int* in_sizes, int n_in,
                              void* d_out, int out_size, void* d_ws, size_t ws_size,
                              hipStream_t stream) {
  const float* x     = (const float*)d_in[0];
  const float* dww   = (const float*)d_in[1];
  const float* dwb   = (const float*)d_in[2];
  const float* gamma = (const float*)d_in[3];
  const float* beta  = (const float*)d_in[4];
  const float* mean  = (const float*)d_in[5];
  const float* var   = (const float*)d_in[6];
  const float* offw  = (const float*)d_in[7];  // [18][128][1][1]
  const float* dfw   = (const float*)d_in[8];  // [128][128][3][3]
  float* out = (float*)d_out;

  // ws layout (floats): xt[4194304] | whi | wlo (147456 shorts each)
  float* xt_ws = (float*)d_ws;
  short* whi = (short*)(xt_ws + (size_t)BB * CC * HWW);
  short* wlo = whi + 36 * 8 * 64 * 8;
  k_prep<<<512 + 72, 256, 0, stream>>>(x, xt_ws, dfw, whi, wlo);
  k_deform_mfma<<<BB * HH, 256, 0, stream>>>(
      x, xt_ws, dww, dwb, gamma, beta, mean, var, offw, whi, wlo, out);
}